// Round 3
// baseline (671.841 us; speedup 1.0000x reference)
//
#include <hip/hip_runtime.h>

typedef short s8v __attribute__((ext_vector_type(8)));
typedef float f32x4 __attribute__((ext_vector_type(4)));
typedef unsigned short u16x4 __attribute__((ext_vector_type(4)));

#define KC 64
#define PAD 72

__device__ __forceinline__ unsigned short f2bf(float x) {
    unsigned int u = __float_as_uint(x);
    u += 0x7fffu + ((u >> 16) & 1u);   // RNE
    return (unsigned short)(u >> 16);
}

__device__ __forceinline__ s8v cvt_frag(const float4 lo, const float4 hi) {
    s8v r;
    r[0] = (short)f2bf(lo.x); r[1] = (short)f2bf(lo.y);
    r[2] = (short)f2bf(lo.z); r[3] = (short)f2bf(lo.w);
    r[4] = (short)f2bf(hi.x); r[5] = (short)f2bf(hi.y);
    r[6] = (short)f2bf(hi.z); r[7] = (short)f2bf(hi.w);
    return r;
}

// Barrier-free GEMM core. Block = 256 thr = 4 waves; block tile 64 m x 128 n.
// Wave w: m-half = w>>1 (32 rows, 2 rt-tiles), n-half = w&1 (64 cols, 4 ct-tiles).
// A fp32 row-major [*][lda] read direct from global (frag rows contiguous in k);
// Bt bf16 [128 n][ldb k] read direct (L2-resident). Ring-2 register pipeline,
// no LDS, no s_barrier -> compiler emits partial vmcnt waits, loads never drain.
__device__ __forceinline__ void gemm_core(
    const float* __restrict__ A, int lda,
    const unsigned short* __restrict__ Bt, int ldb,
    int mbase, int k0, int klen, f32x4 acc[2][4])
{
    const int t    = threadIdx.x;
    const int w    = t >> 6;
    const int lane = t & 63;
    const int quad = lane >> 4;
    const int l16  = lane & 15;
    const int mh   = w >> 1;
    const int nh   = w & 1;

    const float* rA0 = A + (size_t)(mbase + mh * 32 + l16) * lda + k0 + quad * 8;
    const float* rA1 = rA0 + (size_t)16 * lda;
    const unsigned short* rB = Bt + (size_t)(nh * 64 + l16) * ldb + k0 + quad * 8;
    const size_t bstep = (size_t)16 * ldb;

    float4 a[2][2][2][2];   // [slot][rt][kk][half]  64 VGPR
    s8v    b[2][2][4];      // [slot][kk][ct]        64 VGPR
    const int nchunks = klen / KC;

#define LOADC(s, c) do { const size_t o = (size_t)(c) * KC;                    \
        _Pragma("unroll")                                                      \
        for (int kk = 0; kk < 2; ++kk) {                                       \
            a[s][0][kk][0] = *(const float4*)(rA0 + o + kk * 32);              \
            a[s][0][kk][1] = *(const float4*)(rA0 + o + kk * 32 + 4);          \
            a[s][1][kk][0] = *(const float4*)(rA1 + o + kk * 32);              \
            a[s][1][kk][1] = *(const float4*)(rA1 + o + kk * 32 + 4);          \
        }                                                                      \
        _Pragma("unroll")                                                      \
        for (int kk = 0; kk < 2; ++kk)                                         \
            _Pragma("unroll")                                                  \
            for (int ct = 0; ct < 4; ++ct)                                     \
                b[s][kk][ct] = *(const s8v*)(rB + ct * bstep + o + kk * 32);   \
    } while (0)

#define ITER(p)                                                                \
    {                                                                          \
        _Pragma("unroll")                                                      \
        for (int kk = 0; kk < 2; ++kk) {                                       \
            s8v af0 = cvt_frag(a[p][0][kk][0], a[p][0][kk][1]);                \
            s8v af1 = cvt_frag(a[p][1][kk][0], a[p][1][kk][1]);                \
            _Pragma("unroll")                                                  \
            for (int ct = 0; ct < 4; ++ct) {                                   \
                acc[0][ct] = __builtin_amdgcn_mfma_f32_16x16x32_bf16(          \
                    af0, b[p][kk][ct], acc[0][ct], 0, 0, 0);                   \
                acc[1][ct] = __builtin_amdgcn_mfma_f32_16x16x32_bf16(          \
                    af1, b[p][kk][ct], acc[1][ct], 0, 0, 0);                   \
            }                                                                  \
        }                                                                      \
        if (c + 2 < nchunks) LOADC(p, c + 2);                                  \
    }

    LOADC(0, 0);
    if (nchunks > 1) LOADC(1, 1);
    int c = 0;
    while (true) {
        ITER(0)
        if (++c == nchunks) break;
        ITER(1)
        if (++c == nchunks) break;
    }
#undef ITER
#undef LOADC
}

// Split-K partial GEMM: C slab (fp32 [8192][128]) per blockIdx.y.
__global__ __launch_bounds__(256, 2) void gemm_kernel(
    const float* __restrict__ A, int lda,
    const unsigned short* __restrict__ Bt, int ldb,
    float* __restrict__ C, int klen)
{
    f32x4 acc[2][4];
    #pragma unroll
    for (int rt = 0; rt < 2; ++rt)
        #pragma unroll
        for (int ct = 0; ct < 4; ++ct)
            acc[rt][ct] = (f32x4){0.f, 0.f, 0.f, 0.f};

    const int mbase = blockIdx.x * 64;
    gemm_core(A, lda, Bt, ldb, mbase, blockIdx.y * klen, klen, acc);

    C += (size_t)blockIdx.y * 8192 * 128;
    const int t = threadIdx.x;
    const int lane = t & 63, w = t >> 6;
    const int quad = lane >> 4, l16 = lane & 15;
    const int mh = w >> 1, nh = w & 1;
    #pragma unroll
    for (int rt = 0; rt < 2; ++rt) {
        const int row0 = mbase + mh * 32 + rt * 16 + quad * 4;
        #pragma unroll
        for (int ct = 0; ct < 4; ++ct) {
            const int col = nh * 64 + ct * 16 + l16;
            #pragma unroll
            for (int i = 0; i < 4; ++i)
                C[(size_t)(row0 + i) * 128 + col] = acc[rt][ct][i];
        }
    }
}

// G1 fused: xw = x @ W, written bf16-TRANSPOSED to out[128 f][8192 n].
__global__ __launch_bounds__(256, 2) void gemm_xw_kernel(
    const float* __restrict__ x, const unsigned short* __restrict__ Wt,
    unsigned short* __restrict__ out)
{
    f32x4 acc[2][4];
    #pragma unroll
    for (int rt = 0; rt < 2; ++rt)
        #pragma unroll
        for (int ct = 0; ct < 4; ++ct)
            acc[rt][ct] = (f32x4){0.f, 0.f, 0.f, 0.f};

    const int mbase = blockIdx.x * 64;
    gemm_core(x, 128, Wt, 128, mbase, 0, 128, acc);

    const int t = threadIdx.x;
    const int lane = t & 63, w = t >> 6;
    const int quad = lane >> 4, l16 = lane & 15;
    const int mh = w >> 1, nh = w & 1;
    #pragma unroll
    for (int rt = 0; rt < 2; ++rt) {
        const int r0 = mbase + mh * 32 + rt * 16 + quad * 4;
        #pragma unroll
        for (int ct = 0; ct < 4; ++ct) {
            const int f = nh * 64 + ct * 16 + l16;
            u16x4 v;
            v[0] = f2bf(acc[rt][ct][0]); v[1] = f2bf(acc[rt][ct][1]);
            v[2] = f2bf(acc[rt][ct][2]); v[3] = f2bf(acc[rt][ct][3]);
            *(u16x4*)&out[(size_t)f * 8192 + r0] = v;
        }
    }
}

// Transpose+convert: a = nslabs slabs of [nrows][128] fp32.
// out[f][k] = bf16( scale(k) * sum_s a_s[k][f] ), out row stride nrows.
__global__ __launch_bounds__(256) void tkern(
    const float* __restrict__ a, int nslabs,
    const float* __restrict__ dl, const float* __restrict__ ft,
    unsigned short* __restrict__ out, int nrows, int mode)
{
    __shared__ __align__(16) unsigned short L[128 * PAD];
    const int t    = threadIdx.x;
    const int kb   = blockIdx.x * 64;
    const int kloc = t >> 2;
    const int fseg = (t & 3) * 32;
    const int k    = kb + kloc;
    const size_t slab = (size_t)nrows * 128;

    float s = 1.0f;
    if (mode) {
        float s0 = 0.f;
        #pragma unroll
        for (int j = 0; j < 3; ++j) {
            float d = dl[(size_t)j * nrows + k];
            s0 += d * d * ft[(size_t)j * nrows + k];
        }
        s = s0;
    }
    const float* ap = a + (size_t)k * 128 + fseg;
    #pragma unroll
    for (int i = 0; i < 8; ++i) {
        float4 v = *(const float4*)(ap + i * 4);
        for (int sl = 1; sl < nslabs; ++sl) {
            float4 u = *(const float4*)(ap + sl * slab + i * 4);
            v.x += u.x; v.y += u.y; v.z += u.z; v.w += u.w;
        }
        const int fb = fseg + i * 4;
        L[(fb + 0) * PAD + kloc] = f2bf(v.x * s);
        L[(fb + 1) * PAD + kloc] = f2bf(v.y * s);
        L[(fb + 2) * PAD + kloc] = f2bf(v.z * s);
        L[(fb + 3) * PAD + kloc] = f2bf(v.w * s);
    }
    __syncthreads();
    const int f    = t >> 1;
    const int half = (t & 1) * 32;
    unsigned short* op = out + (size_t)f * nrows + kb + half;
    #pragma unroll
    for (int i = 0; i < 4; ++i) {
        *(s8v*)(op + i * 8) = *(const s8v*)&L[f * PAD + half + i * 8];
    }
}

// out = sum of 4 partial slabs + bias
__global__ __launch_bounds__(256) void addbias_kernel(
    const float* __restrict__ p, const float* __restrict__ bias,
    float* __restrict__ out)
{
    const size_t e = ((size_t)blockIdx.x * 256 + threadIdx.x) * 4;
    const size_t slab = (size_t)8192 * 128;
    float4 r = *(const float4*)(bias + (e & 127));
    #pragma unroll
    for (int s = 0; s < 4; ++s) {
        float4 x = *(const float4*)(p + s * slab + e);
        r.x += x.x; r.y += x.y; r.z += x.z; r.w += x.w;
    }
    *(float4*)(out + e) = r;
}

extern "C" void kernel_launch(void* const* d_in, const int* in_sizes, int n_in,
                              void* d_out, int out_size, void* d_ws, size_t ws_size,
                              hipStream_t stream)
{
    const float* x  = (const float*)d_in[0];   // [8192][128]
    const float* dl = (const float*)d_in[1];   // [3][8192]
    const float* U  = (const float*)d_in[2];   // [8192][8192]
    const float* Vt = (const float*)d_in[3];   // [8192][8192]
    const float* W  = (const float*)d_in[4];   // [128][128]
    const float* ft = (const float*)d_in[5];   // [3][8192]
    const float* bs = (const float*)d_in[6];   // [128]
    float* out = (float*)d_out;

    const int N = 8192;
    const int SPLITK = 4;
    char* ws = (char*)d_ws;
    unsigned short* Wt  = (unsigned short*)(ws);                           // 32KB (64KB reserved)
    unsigned short* xwt = (unsigned short*)(ws + (64 << 10));              // 2MB bf16 [128][8192]
    unsigned short* yt  = (unsigned short*)(ws + (64 << 10) + (2 << 20));  // 2MB bf16 [128][8192]
    float* bufA = (float*)(ws + (64 << 10) + (4 << 20));                   // 16MB: out partials x4
    float* bufB = (float*)(ws + (64 << 10) + (20 << 20));                  // 16MB: y partials x4

    // T0: Wt[f][c] = bf16(W[c][f])
    tkern<<<dim3(2), 256, 0, stream>>>(W, 1, nullptr, nullptr, Wt, 128, 0);
    // G1: xwt[f][n] = bf16( (x @ W)[n][f] )   (fused transpose-out)
    gemm_xw_kernel<<<dim3(N / 64), 256, 0, stream>>>(x, Wt, xwt);
    // G2: y partials = Vt @ xw  (split-K 4)
    gemm_kernel<<<dim3(N / 64, SPLITK), 256, 0, stream>>>(Vt, N, xwt, N, bufB, N / SPLITK);
    // T2: yt[f][k] = bf16( scale(k) * sum_s y_s[k][f] )
    tkern<<<dim3(N / 64), 256, 0, stream>>>(bufB, SPLITK, dl, ft, yt, N, 1);
    // G3: out partials = U @ y  (split-K 4)
    gemm_kernel<<<dim3(N / 64, SPLITK), 256, 0, stream>>>(U, N, yt, N, bufA, N / SPLITK);
    // T3: out = sum partials + bias
    addbias_kernel<<<dim3((N * 128) / (256 * 4)), 256, 0, stream>>>(bufA, bs, out);
}

// Round 4
// 612.387 us; speedup vs baseline: 1.0971x; 1.0971x over previous
//
#include <hip/hip_runtime.h>

typedef short s8v __attribute__((ext_vector_type(8)));
typedef float f32x4 __attribute__((ext_vector_type(4)));
typedef unsigned short u16x4 __attribute__((ext_vector_type(4)));

#define KC 32
#define PAD 72

__device__ __forceinline__ unsigned short f2bf(float x) {
    unsigned int u = __float_as_uint(x);
    u += 0x7fffu + ((u >> 16) & 1u);   // RNE
    return (unsigned short)(u >> 16);
}

__device__ __forceinline__ s8v cvt8(const f32x4 lo, const f32x4 hi) {
    s8v r;
    r[0] = (short)f2bf(lo[0]); r[1] = (short)f2bf(lo[1]);
    r[2] = (short)f2bf(lo[2]); r[3] = (short)f2bf(lo[3]);
    r[4] = (short)f2bf(hi[0]); r[5] = (short)f2bf(hi[1]);
    r[6] = (short)f2bf(hi[2]); r[7] = (short)f2bf(hi[3]);
    return r;
}

// async 16B global->LDS DMA (no VGPR round trip)
__device__ __forceinline__ void gl2lds16(const void* g, void* l) {
    __builtin_amdgcn_global_load_lds(
        (const __attribute__((address_space(1))) unsigned int*)g,
        (__attribute__((address_space(3))) unsigned int*)l, 16, 0, 0);
}

// C[m][f] = sum_k A[m][k]*B[k][f].  A fp32 row-major [M][lda] streamed from HBM
// via global_load_lds into a 3-slot LDS ring; Bt bf16 [128 f][ldb k] (L2-resident)
// likewise. Hand-placed s_waitcnt vmcnt(4) + raw s_barrier: the wait for slot c
// lands 2 BW-paced iterations after issue (never vmcnt(0) until the tail).
// Block: 256 thr / 4 waves; tile 64m x 128n; KC=32 -> 8 MFMA/chunk/wave.
// LDS slot: A [64 rows][128B] fp32 + B [128 rows][64B] bf16, XOR-swizzled
// 16B granules (swizzle applied on the *global source* so DMA stays coalesced).
// EPI 0: fp32 partial slab at Cout + blockIdx.y*Mtot*128 (split-K).
// EPI 1: bf16 transposed out[f][Mtot].
template<int EPI>
__global__ __launch_bounds__(256, 2) void gemm_dma(
    const float* __restrict__ A, int lda,
    const unsigned short* __restrict__ Bt, int ldb,
    void* __restrict__ Cout, int klen, int Mtot)
{
    __shared__ __align__(16) unsigned char ring[3][16384];  // 48 KB -> 2 blocks/CU

    const int t    = threadIdx.x;
    const int w    = t >> 6;
    const int lane = t & 63;
    const int quad = lane >> 4;
    const int l16  = lane & 15;
    const int mh   = w >> 1;
    const int nh   = w & 1;

    const int mbase   = blockIdx.x * 64;
    const int k0      = blockIdx.y * klen;
    const int nchunks = klen / KC;

    // ---- DMA source mapping (per thread, 2 A-insts + 2 B-insts per chunk) ----
    // A: inst j: LDS linear L=(j*4+w)*1024+lane*16 -> row r=L/128, granule p=lane&7.
    //    source granule g = p ^ (r&7)  (XOR swizzle in LDS k-order).
    int arow[2], aoff[2];
    #pragma unroll
    for (int j = 0; j < 2; ++j) {
        const int r = (j * 4 + w) * 8 + (lane >> 3);
        arow[j] = r;
        aoff[j] = (((lane & 7) ^ (r & 7)) * 4);   // float offset within chunk
    }
    // B: row n=L/64, granule p=lane&3; source granule g = p ^ (n&3).
    int bnrow[2], bnoff[2];
    #pragma unroll
    for (int j = 0; j < 2; ++j) {
        const int n = (j * 4 + w) * 16 + (lane >> 2);
        bnrow[j] = n;
        bnoff[j] = (((lane & 3) ^ (n & 3)) * 8);  // bf16 offset within chunk
    }
    const float* Abase = A + (size_t)mbase * lda + k0;
    const int ldsoff0 = (0 * 4 + w) * 1024 + lane * 16;
    const int ldsoff1 = (1 * 4 + w) * 1024 + lane * 16;

#define ISSUE(s, c) do {                                                       \
        const int co_ = (c) * KC;                                              \
        gl2lds16(Abase + (size_t)arow[0] * lda + co_ + aoff[0],                \
                 &ring[s][ldsoff0]);                                           \
        gl2lds16(Abase + (size_t)arow[1] * lda + co_ + aoff[1],                \
                 &ring[s][ldsoff1]);                                           \
        gl2lds16(Bt + (size_t)bnrow[0] * ldb + k0 + co_ + bnoff[0],            \
                 &ring[s][8192 + ldsoff0]);                                    \
        gl2lds16(Bt + (size_t)bnrow[1] * ldb + k0 + co_ + bnoff[1],            \
                 &ring[s][8192 + ldsoff1]);                                    \
    } while (0)

    f32x4 acc[2][4];
    #pragma unroll
    for (int rt = 0; rt < 2; ++rt)
        #pragma unroll
        for (int ct = 0; ct < 4; ++ct)
            acc[rt][ct] = (f32x4){0.f, 0.f, 0.f, 0.f};

    // prologue: chunks 0,1 in flight (8 vm ops/thread)
    ISSUE(0, 0);
    ISSUE(1, 1);

    // fragment read constants
    const int aph0 = (quad * 2 + 0);
    const int aph1 = (quad * 2 + 1);
    const int asw  = l16 & 7;       // row&7 for A rows (mh*32+rt*16+l16)
    const int bsw  = l16 & 3;       // n&3  for B rows

    for (int c = 0; c < nchunks; ++c) {
        const int s = c % 3;
        // wait slot s's DMA (issued 2 iters ago); keep next chunk's 4 in flight
        if (c + 1 < nchunks)
            asm volatile("s_waitcnt vmcnt(4) lgkmcnt(0)\n\ts_barrier" ::: "memory");
        else
            asm volatile("s_waitcnt vmcnt(0) lgkmcnt(0)\n\ts_barrier" ::: "memory");
        if (c + 2 < nchunks) ISSUE((c + 2) % 3, c + 2);

        const unsigned char* sa = &ring[s][0];
        const unsigned char* sb = &ring[s][8192];
        s8v af[2], bfr[4];
        #pragma unroll
        for (int rt = 0; rt < 2; ++rt) {
            const int row = mh * 32 + rt * 16 + l16;
            f32x4 lo = *(const f32x4*)(sa + row * 128 + ((aph0 ^ asw) * 16));
            f32x4 hi = *(const f32x4*)(sa + row * 128 + ((aph1 ^ asw) * 16));
            af[rt] = cvt8(lo, hi);
        }
        #pragma unroll
        for (int ct = 0; ct < 4; ++ct) {
            const int n = nh * 64 + ct * 16 + l16;
            bfr[ct] = *(const s8v*)(sb + n * 64 + ((quad ^ bsw) * 16));
        }
        #pragma unroll
        for (int rt = 0; rt < 2; ++rt)
            #pragma unroll
            for (int ct = 0; ct < 4; ++ct)
                acc[rt][ct] = __builtin_amdgcn_mfma_f32_16x16x32_bf16(
                    af[rt], bfr[ct], acc[rt][ct], 0, 0, 0);
    }
#undef ISSUE

    // epilogue: C/D layout col = lane&15, row = quad*4 + reg
    if (EPI == 0) {
        float* C = (float*)Cout + (size_t)blockIdx.y * Mtot * 128;
        #pragma unroll
        for (int rt = 0; rt < 2; ++rt) {
            const int row0 = mbase + mh * 32 + rt * 16 + quad * 4;
            #pragma unroll
            for (int ct = 0; ct < 4; ++ct) {
                const int col = nh * 64 + ct * 16 + l16;
                #pragma unroll
                for (int i = 0; i < 4; ++i)
                    C[(size_t)(row0 + i) * 128 + col] = acc[rt][ct][i];
            }
        }
    } else {
        unsigned short* O = (unsigned short*)Cout;
        #pragma unroll
        for (int rt = 0; rt < 2; ++rt) {
            const int r0 = mbase + mh * 32 + rt * 16 + quad * 4;
            #pragma unroll
            for (int ct = 0; ct < 4; ++ct) {
                const int f = nh * 64 + ct * 16 + l16;
                u16x4 v;
                v[0] = f2bf(acc[rt][ct][0]); v[1] = f2bf(acc[rt][ct][1]);
                v[2] = f2bf(acc[rt][ct][2]); v[3] = f2bf(acc[rt][ct][3]);
                *(u16x4*)&O[(size_t)f * Mtot + r0] = v;
            }
        }
    }
}

// Transpose+convert: a = nslabs slabs of [nrows][128] fp32.
// out[f][k] = bf16( scale(k) * sum_s a_s[k][f] ), out row stride nrows.
__global__ __launch_bounds__(256) void tkern(
    const float* __restrict__ a, int nslabs,
    const float* __restrict__ dl, const float* __restrict__ ft,
    unsigned short* __restrict__ out, int nrows, int mode)
{
    __shared__ __align__(16) unsigned short L[128 * PAD];
    const int t    = threadIdx.x;
    const int kb   = blockIdx.x * 64;
    const int kloc = t >> 2;
    const int fseg = (t & 3) * 32;
    const int k    = kb + kloc;
    const size_t slab = (size_t)nrows * 128;

    float s = 1.0f;
    if (mode) {
        float s0 = 0.f;
        #pragma unroll
        for (int j = 0; j < 3; ++j) {
            float d = dl[(size_t)j * nrows + k];
            s0 += d * d * ft[(size_t)j * nrows + k];
        }
        s = s0;
    }
    const float* ap = a + (size_t)k * 128 + fseg;
    #pragma unroll
    for (int i = 0; i < 8; ++i) {
        float4 v = *(const float4*)(ap + i * 4);
        for (int sl = 1; sl < nslabs; ++sl) {
            float4 u = *(const float4*)(ap + sl * slab + i * 4);
            v.x += u.x; v.y += u.y; v.z += u.z; v.w += u.w;
        }
        const int fb = fseg + i * 4;
        L[(fb + 0) * PAD + kloc] = f2bf(v.x * s);
        L[(fb + 1) * PAD + kloc] = f2bf(v.y * s);
        L[(fb + 2) * PAD + kloc] = f2bf(v.z * s);
        L[(fb + 3) * PAD + kloc] = f2bf(v.w * s);
    }
    __syncthreads();
    const int f    = t >> 1;
    const int half = (t & 1) * 32;
    unsigned short* op = out + (size_t)f * nrows + kb + half;
    #pragma unroll
    for (int i = 0; i < 4; ++i) {
        *(s8v*)(op + i * 8) = *(const s8v*)&L[f * PAD + half + i * 8];
    }
}

// out = sum of 4 partial slabs + bias
__global__ __launch_bounds__(256) void addbias_kernel(
    const float* __restrict__ p, const float* __restrict__ bias,
    float* __restrict__ out)
{
    const size_t e = ((size_t)blockIdx.x * 256 + threadIdx.x) * 4;
    const size_t slab = (size_t)8192 * 128;
    float4 r = *(const float4*)(bias + (e & 127));
    #pragma unroll
    for (int s = 0; s < 4; ++s) {
        float4 x = *(const float4*)(p + s * slab + e);
        r.x += x.x; r.y += x.y; r.z += x.z; r.w += x.w;
    }
    *(float4*)(out + e) = r;
}

extern "C" void kernel_launch(void* const* d_in, const int* in_sizes, int n_in,
                              void* d_out, int out_size, void* d_ws, size_t ws_size,
                              hipStream_t stream)
{
    const float* x  = (const float*)d_in[0];   // [8192][128]
    const float* dl = (const float*)d_in[1];   // [3][8192]
    const float* U  = (const float*)d_in[2];   // [8192][8192]
    const float* Vt = (const float*)d_in[3];   // [8192][8192]
    const float* W  = (const float*)d_in[4];   // [128][128]
    const float* ft = (const float*)d_in[5];   // [3][8192]
    const float* bs = (const float*)d_in[6];   // [128]
    float* out = (float*)d_out;

    const int N = 8192;
    const int SPLITK = 4;
    char* ws = (char*)d_ws;
    unsigned short* Wt  = (unsigned short*)(ws);                           // 32KB (64KB reserved)
    unsigned short* xwt = (unsigned short*)(ws + (64 << 10));              // 2MB bf16 [128][8192]
    unsigned short* yt  = (unsigned short*)(ws + (64 << 10) + (2 << 20));  // 2MB bf16 [128][8192]
    float* bufA = (float*)(ws + (64 << 10) + (4 << 20));                   // 16MB: out partials x4
    float* bufB = (float*)(ws + (64 << 10) + (20 << 20));                  // 16MB: y partials x4

    // T0: Wt[f][c] = bf16(W[c][f])
    tkern<<<dim3(2), 256, 0, stream>>>(W, 1, nullptr, nullptr, Wt, 128, 0);
    // G1: xwt[f][n] = bf16( (x @ W)[n][f] )   (fused transpose-out)
    gemm_dma<1><<<dim3(N / 64, 1), 256, 0, stream>>>(x, 128, Wt, 128, xwt, 128, N);
    // G2: y partials = Vt @ xw  (split-K 4)
    gemm_dma<0><<<dim3(N / 64, SPLITK), 256, 0, stream>>>(Vt, N, xwt, N, bufB, N / SPLITK, N);
    // T2: yt[f][k] = bf16( scale(k) * sum_s y_s[k][f] )
    tkern<<<dim3(N / 64), 256, 0, stream>>>(bufB, SPLITK, dl, ft, yt, N, 1);
    // G3: out partials = U @ y  (split-K 4)
    gemm_dma<0><<<dim3(N / 64, SPLITK), 256, 0, stream>>>(U, N, yt, N, bufA, N / SPLITK, N);
    // T3: out = sum partials + bias
    addbias_kernel<<<dim3((N * 128) / (256 * 4)), 256, 0, stream>>>(bufA, bs, out);
}